// Round 3
// baseline (3623.827 us; speedup 1.0000x reference)
//
#include <hip/hip_runtime.h>

using u32 = unsigned int;
using u64 = unsigned long long;
using bf16x8 = __attribute__((ext_vector_type(8))) short;
using f32x4  = __attribute__((ext_vector_type(4))) float;

// Problem constants
#define BB_ 64
#define TT_ 512
#define II_ 1024
#define HH_ 1024
#define NSCAN_BLOCKS 256   // 64 j-groups x 4 batch-groups

__device__ __forceinline__ unsigned short bf16rne(float f) {
  u32 u = __float_as_uint(f);
  return (unsigned short)((u + 0x7FFFu + ((u >> 16) & 1u)) >> 16);
}
__device__ __forceinline__ u32 pk2(float a, float b) {
  u32 ua = __float_as_uint(a), ub = __float_as_uint(b);
  u32 lo = (ua + 0x7FFFu + ((ua >> 16) & 1u)) >> 16;
  u32 hi = (ub + 0x7FFFu + ((ub >> 16) & 1u)) & 0xFFFF0000u;
  return lo | hi;
}
__device__ __forceinline__ void gll16(const void* g, void* s) {
  __builtin_amdgcn_global_load_lds(
      (const __attribute__((address_space(1))) u32*)g,
      (__attribute__((address_space(3))) u32*)s, 16, 0, 0);
}
// fast tanh: 1 - 2/(exp2(2*log2e*x)+1); |err| < 1e-6, exact +-1 saturation
__device__ __forceinline__ float tanhfast(float x) {
  float e = __builtin_amdgcn_exp2f(x * 2.885390081777927f);
  return 1.0f - 2.0f / (e + 1.0f);
}

__device__ __forceinline__ void cvt4(const float* __restrict__ s, unsigned short* __restrict__ d, long long g) {
  float4 v = ((const float4*)s)[g];
  ushort4 o;
  o.x = bf16rne(v.x); o.y = bf16rne(v.y); o.z = bf16rne(v.z); o.w = bf16rne(v.w);
  ((ushort4*)d)[g] = o;
}

// ---------------------------------------------------------------------------
// k_convert: bf16 copies of x / W_ih / [W_hh1;W_hh2]; hbuf[0] = tagged h0
// (u32 = bf16<<16 | tag0). Re-runs fully each launch -> graph-replay safe.
// ---------------------------------------------------------------------------
__global__ void k_convert(const float* __restrict__ x, const float* __restrict__ h0,
                          const float* __restrict__ Wih, const float* __restrict__ Wh1,
                          const float* __restrict__ Wh2,
                          unsigned short* __restrict__ xb, unsigned short* __restrict__ Wihb,
                          unsigned short* __restrict__ Wcatb, u32* __restrict__ hbuf,
                          int do_x) {
  const long long NWI = (long long)HH_ * II_ / 4;
  const long long NH0 = (long long)BB_ * HH_ / 4;
  const long long NX  = do_x ? ((long long)BB_ * TT_ * II_ / 4) : 0;
  const long long total = 3 * NWI + NH0 + NX;
  for (long long g = (long long)blockIdx.x * blockDim.x + threadIdx.x; g < total;
       g += (long long)gridDim.x * blockDim.x) {
    if (g < NWI) {
      cvt4(Wih, Wihb, g);
    } else if (g < 2 * NWI) {
      cvt4(Wh1, Wcatb, g - NWI);
    } else if (g < 3 * NWI) {
      cvt4(Wh2, Wcatb + (long long)HH_ * II_, g - 2 * NWI);
    } else if (g < 3 * NWI + NH0) {
      long long gg = g - 3 * NWI;
      float4 v = ((const float4*)h0)[gg];
      uint4 o;
      o.x = (u32)bf16rne(v.x) << 16;  // tag = 0
      o.y = (u32)bf16rne(v.y) << 16;
      o.z = (u32)bf16rne(v.z) << 16;
      o.w = (u32)bf16rne(v.w) << 16;
      ((uint4*)hbuf)[gg] = o;
    } else {
      cvt4(x, xb, g - (3 * NWI + NH0));
    }
  }
}

// ---------------------------------------------------------------------------
// k_gemm: xp = x @ Wih^T + b_ih, written into d_out. (unchanged, verified)
// ---------------------------------------------------------------------------
template <bool XB>
__global__ __launch_bounds__(256) void k_gemm(const unsigned short* __restrict__ xbg,
                                              const float* __restrict__ xf,
                                              const unsigned short* __restrict__ Wb,
                                              const float* __restrict__ bias,
                                              float* __restrict__ C) {
  __shared__ __align__(16) unsigned short ldsA[128 * 64];
  __shared__ __align__(16) unsigned short ldsB[128 * 64];
  const int tid = threadIdx.x;
  const int w = tid >> 6, l = tid & 63;
  const int lr = l & 15, lk = l >> 4;
  const int n0 = (blockIdx.x & 7) * 128;
  const int m0 = (blockIdx.x >> 3) * 128;
  const int mbase = (w >> 1) * 64, nbase = (w & 1) * 64;

  f32x4 acc[4][4] = {};

  for (int kb = 0; kb < 16; ++kb) {
    const int k0 = kb * 64;
#pragma unroll
    for (int r = 0; r < 4; ++r) {
      int tb = r * 4096 + w * 1024 + l * 16;
      int row = tb >> 7;
      int p = (tb >> 4) & 7;
      int c = p ^ (row & 7);
      gll16(Wb + (u64)(n0 + row) * II_ + k0 + c * 8,
            (char*)ldsB + r * 4096 + w * 1024);
    }
    if constexpr (XB) {
#pragma unroll
      for (int r = 0; r < 4; ++r) {
        int tb = r * 4096 + w * 1024 + l * 16;
        int row = tb >> 7;
        int p = (tb >> 4) & 7;
        int c = p ^ (row & 7);
        gll16(xbg + (u64)(m0 + row) * II_ + k0 + c * 8,
              (char*)ldsA + r * 4096 + w * 1024);
      }
    } else {
      const int r = tid >> 1, ch = tid & 1;
      const float* gs = xf + (u64)(m0 + r) * II_ + k0 + ch * 32;
      float4 v[8];
#pragma unroll
      for (int q = 0; q < 8; ++q) v[q] = ((const float4*)gs)[q];
#pragma unroll
      for (int q = 0; q < 4; ++q) {
        int c = ch * 4 + q;
        int p = c ^ (r & 7);
        uint4 pk;
        pk.x = pk2(v[2 * q].x, v[2 * q].y);
        pk.y = pk2(v[2 * q].z, v[2 * q].w);
        pk.z = pk2(v[2 * q + 1].x, v[2 * q + 1].y);
        pk.w = pk2(v[2 * q + 1].z, v[2 * q + 1].w);
        *(uint4*)((char*)ldsA + r * 128 + p * 16) = pk;
      }
    }
    __syncthreads();

    bf16x8 a[4][2], b[4][2];
#pragma unroll
    for (int mt = 0; mt < 4; ++mt) {
      int row = mbase + mt * 16 + lr;
#pragma unroll
      for (int kk = 0; kk < 2; ++kk) {
        int c = kk * 4 + lk, p = c ^ (row & 7);
        a[mt][kk] = *(const bf16x8*)((const char*)ldsA + row * 128 + p * 16);
      }
    }
#pragma unroll
    for (int nt = 0; nt < 4; ++nt) {
      int row = nbase + nt * 16 + lr;
#pragma unroll
      for (int kk = 0; kk < 2; ++kk) {
        int c = kk * 4 + lk, p = c ^ (row & 7);
        b[nt][kk] = *(const bf16x8*)((const char*)ldsB + row * 128 + p * 16);
      }
    }
#pragma unroll
    for (int kk = 0; kk < 2; ++kk)
#pragma unroll
      for (int mt = 0; mt < 4; ++mt)
#pragma unroll
        for (int nt = 0; nt < 4; ++nt)
          acc[mt][nt] = __builtin_amdgcn_mfma_f32_16x16x32_bf16(a[mt][kk], b[nt][kk], acc[mt][nt], 0, 0, 0);
    __syncthreads();
  }

  float bn[4];
#pragma unroll
  for (int nt = 0; nt < 4; ++nt) bn[nt] = bias[n0 + nbase + nt * 16 + lr];
#pragma unroll
  for (int mt = 0; mt < 4; ++mt) {
#pragma unroll
    for (int i = 0; i < 4; ++i) {
      int m = m0 + mbase + mt * 16 + lk * 4 + i;
      float* cr = C + (u64)m * HH_ + n0 + nbase + lr;
#pragma unroll
      for (int nt = 0; nt < 4; ++nt) cr[nt * 16] = acc[mt][nt][i] + bn[nt];
    }
  }
}

// ---------------------------------------------------------------------------
// k_scan v3: tag-in-data protocol. 256 blocks = 64 j-groups (16 cols) x 4
// batch-groups (16 rows). h exchanged as tagged u32 (bf16<<16 | step).
// Consumer polls its own MFMA operand words until all tags == t; the poll's
// registers ARE the data (1 LLC round trip for sync+data). Producer fires
// relaxed stores and moves on (no ack, no flags). Double buffer + tag
// disambiguation (skew <= 1 step) => race-free.
// Weights: wt[2][8] = 64 VGPR per thread, register-resident.
// ---------------------------------------------------------------------------
__global__ __launch_bounds__(256) void k_scan(float* __restrict__ out, const float* __restrict__ h0,
                                              const float* __restrict__ b1, const float* __restrict__ b2,
                                              const unsigned short* __restrict__ Wcat,
                                              u32* __restrict__ hbuf) {
  __shared__ float part[2112];  // [(w*2+nt)*4+i][66] padded
  const int tid = threadIdx.x, w = tid >> 6, l = tid & 63;
  const int lr = l & 15, lk = l >> 4;
  const int og = blockIdx.x & 63, bg = blockIdx.x >> 6;
  const int jb = og * 16, bb = bg * 16;
  const int koff = w * 256;

  // --- persistent weights: wt[nt][kk], nt 0 -> W_hh1 rows, 1 -> W_hh2 ---
  bf16x8 wt[2][8];
#pragma unroll
  for (int nt = 0; nt < 2; ++nt) {
    int nrow = (nt == 0) ? (jb + lr) : (HH_ + jb + lr);
    const unsigned short* wr = Wcat + (u64)nrow * HH_ + koff + lk * 8;
#pragma unroll
    for (int kk = 0; kk < 8; ++kk) wt[nt][kk] = *(const bf16x8*)(wr + kk * 32);
  }

  // --- per-thread epilogue state: one (row m, col jc), both gates ---
  const int m = tid >> 4, jc = tid & 15;
  const float bvA = b1[jb + jc], bvB = b2[jb + jc];
  float hold = h0[(u64)(bb + m) * HH_ + jb + jc];
  float* outp  = out + (u64)(bb + m) * TT_ * HH_ + jb + jc;   // + t*HH_ per step
  u32* hst0 = hbuf + (u64)(bb + m) * HH_ + jb + jc;           // store slot, buf 0

  const u64* hb0 = (const u64*)hbuf;
  const u64 myw = ((u64)(bb + lr) * HH_ + koff + lk * 8) >> 1;  // u64 index
  const u32 HB2 = BB_ * HH_ / 2;  // u64 elems per buffer

  for (int t = 0; t < TT_; ++t) {
    // xp prefetch (latency hides under the poll)
    float xpv = outp[(u64)t * HH_];

    // --- poll own operand words until all tags == t ---
    const u64* hB = hb0 + (u64)(t & 1) * HB2 + myw;
    const u32 expt = (u32)t;
    u64 qv[32];
    while (true) {
#pragma unroll
      for (int kk = 0; kk < 8; ++kk)
#pragma unroll
        for (int q = 0; q < 4; ++q)
          qv[kk * 4 + q] = __hip_atomic_load(hB + kk * 16 + q, __ATOMIC_RELAXED, __HIP_MEMORY_SCOPE_AGENT);
      u32 bad = 0;
#pragma unroll
      for (int i = 0; i < 32; ++i) {
        bad |= ((u32)qv[i] ^ expt);
        bad |= ((u32)(qv[i] >> 32) ^ expt);
      }
      if (__all((int)((bad & 0xFFFFu) == 0))) break;
      __builtin_amdgcn_s_sleep(1);
    }

    // --- unpack high-halves -> bf16 frags, MFMA ---
    f32x4 acc[2] = {};
#pragma unroll
    for (int kk = 0; kk < 8; ++kk) {
      union { u32 u[4]; bf16x8 v; } au;
#pragma unroll
      for (int q = 0; q < 4; ++q) {
        u64 d = qv[kk * 4 + q];
        au.u[q] = __builtin_amdgcn_perm((u32)(d >> 32), (u32)d, 0x07060302);
      }
#pragma unroll
      for (int nt = 0; nt < 2; ++nt)
        acc[nt] = __builtin_amdgcn_mfma_f32_16x16x32_bf16(au.v, wt[nt][kk], acc[nt], 0, 0, 0);
    }

    // --- cross-wave K-reduction via LDS ---
#pragma unroll
    for (int nt = 0; nt < 2; ++nt)
#pragma unroll
      for (int i = 0; i < 4; ++i)
        part[((w * 2 + nt) * 4 + i) * 66 + l] = acc[nt][i];
    __syncthreads();

    float v1 = 0.f, v2 = 0.f;
    {
      const int ridx = (m & 3), lidx = (m >> 2) * 16 + jc;
#pragma unroll
      for (int ww = 0; ww < 4; ++ww) {
        v1 += part[((ww * 2 + 0) * 4 + ridx) * 66 + lidx];
        v2 += part[((ww * 2 + 1) * 4 + ridx) * 66 + lidx];
      }
    }
    __syncthreads();  // part[] WAR for next step

    // --- gates (scalar per thread) ---
    float t1 = tanhfast(v1 + xpv + bvA);
    float t2 = tanhfast(v2 + xpv + bvB);
    float hn = t1 + hold * (t2 - t1);  // (1-h)*v1 + h*v2
    hold = hn;
    outp[(u64)t * HH_] = hn;
    if (t < TT_ - 1) {
      u32 tagged = ((u32)bf16rne(hn) << 16) | (u32)(t + 1);
      __hip_atomic_store(hst0 + (u64)((t + 1) & 1) * (BB_ * HH_), tagged,
                         __ATOMIC_RELAXED, __HIP_MEMORY_SCOPE_AGENT);
    } else {
      out[(u64)BB_ * TT_ * HH_ + (u64)(bb + m) * HH_ + jb + jc] = hn;
    }
  }
}

// ---------------------------------------------------------------------------
extern "C" void kernel_launch(void* const* d_in, const int* in_sizes, int n_in,
                              void* d_out, int out_size, void* d_ws, size_t ws_size,
                              hipStream_t stream) {
  const float* x    = (const float*)d_in[0];
  const float* h0   = (const float*)d_in[1];
  const float* Wih  = (const float*)d_in[2];
  const float* bih  = (const float*)d_in[3];
  const float* Whh1 = (const float*)d_in[4];
  const float* bhh1 = (const float*)d_in[5];
  const float* Whh2 = (const float*)d_in[6];
  const float* bhh2 = (const float*)d_in[7];
  float* out = (float*)d_out;

  char* ws = (char*)d_ws;
  unsigned short* Wihb  = (unsigned short*)(ws + 0);          //  2 MiB
  unsigned short* Wcatb = (unsigned short*)(ws + 2097152);    //  4 MiB
  u32*            hbuf  = (u32*)(ws + 6291456);               //  512 KiB (2 tagged buffers)
  unsigned short* xb    = (unsigned short*)(ws + 6815744);    //  64 MiB
  const bool fastx = ws_size >= 73924608ULL;

  hipLaunchKernelGGL(k_convert, dim3(2048), dim3(256), 0, stream,
                     x, h0, Wih, Whh1, Whh2, xb, Wihb, Wcatb, hbuf, (int)fastx);
  if (fastx)
    hipLaunchKernelGGL((k_gemm<true>), dim3(2048), dim3(256), 0, stream,
                       xb, (const float*)nullptr, Wihb, bih, out);
  else
    hipLaunchKernelGGL((k_gemm<false>), dim3(2048), dim3(256), 0, stream,
                       (const unsigned short*)nullptr, x, Wihb, bih, out);
  hipLaunchKernelGGL(k_scan, dim3(NSCAN_BLOCKS), dim3(256), 0, stream,
                     out, h0, bhh1, bhh2, Wcatb, hbuf);
}

// Round 4
// 3046.412 us; speedup vs baseline: 1.1895x; 1.1895x over previous
//
#include <hip/hip_runtime.h>

using u32 = unsigned int;
using u64 = unsigned long long;
using bf16x8 = __attribute__((ext_vector_type(8))) short;
using f32x4  = __attribute__((ext_vector_type(4))) float;

// Problem constants
#define BB_ 64
#define TT_ 512
#define II_ 1024
#define HH_ 1024
#define NSCAN_BLOCKS 128   // 32 j-groups (32 cols) x 4 batch-groups (16 rows)

__device__ __forceinline__ unsigned short bf16rne(float f) {
  u32 u = __float_as_uint(f);
  return (unsigned short)((u + 0x7FFFu + ((u >> 16) & 1u)) >> 16);
}
__device__ __forceinline__ u32 pk2(float a, float b) {
  u32 ua = __float_as_uint(a), ub = __float_as_uint(b);
  u32 lo = (ua + 0x7FFFu + ((ua >> 16) & 1u)) >> 16;
  u32 hi = (ub + 0x7FFFu + ((ub >> 16) & 1u)) & 0xFFFF0000u;
  return lo | hi;
}
__device__ __forceinline__ void gll16(const void* g, void* s) {
  __builtin_amdgcn_global_load_lds(
      (const __attribute__((address_space(1))) u32*)g,
      (__attribute__((address_space(3))) u32*)s, 16, 0, 0);
}
// fast tanh: 1 - 2/(exp2(2*log2e*x)+1); |err| < 1e-6, exact +-1 saturation
__device__ __forceinline__ float tanhfast(float x) {
  float e = __builtin_amdgcn_exp2f(x * 2.885390081777927f);
  return 1.0f - 2.0f / (e + 1.0f);
}

__device__ __forceinline__ void cvt4(const float* __restrict__ s, unsigned short* __restrict__ d, long long g) {
  float4 v = ((const float4*)s)[g];
  ushort4 o;
  o.x = bf16rne(v.x); o.y = bf16rne(v.y); o.z = bf16rne(v.z); o.w = bf16rne(v.w);
  ((ushort4*)d)[g] = o;
}

// ---------------------------------------------------------------------------
// k_convert: bf16 copies of x / W_ih / [W_hh1;W_hh2]; hbuf[0] = tagged h0
// (u32 = bf16<<16 | tag0). Re-runs fully each launch -> graph-replay safe.
// ---------------------------------------------------------------------------
__global__ void k_convert(const float* __restrict__ x, const float* __restrict__ h0,
                          const float* __restrict__ Wih, const float* __restrict__ Wh1,
                          const float* __restrict__ Wh2,
                          unsigned short* __restrict__ xb, unsigned short* __restrict__ Wihb,
                          unsigned short* __restrict__ Wcatb, u32* __restrict__ hbuf,
                          int do_x) {
  const long long NWI = (long long)HH_ * II_ / 4;
  const long long NH0 = (long long)BB_ * HH_ / 4;
  const long long NX  = do_x ? ((long long)BB_ * TT_ * II_ / 4) : 0;
  const long long total = 3 * NWI + NH0 + NX;
  for (long long g = (long long)blockIdx.x * blockDim.x + threadIdx.x; g < total;
       g += (long long)gridDim.x * blockDim.x) {
    if (g < NWI) {
      cvt4(Wih, Wihb, g);
    } else if (g < 2 * NWI) {
      cvt4(Wh1, Wcatb, g - NWI);
    } else if (g < 3 * NWI) {
      cvt4(Wh2, Wcatb + (long long)HH_ * II_, g - 2 * NWI);
    } else if (g < 3 * NWI + NH0) {
      long long gg = g - 3 * NWI;
      float4 v = ((const float4*)h0)[gg];
      uint4 o;
      o.x = (u32)bf16rne(v.x) << 16;  // tag = 0
      o.y = (u32)bf16rne(v.y) << 16;
      o.z = (u32)bf16rne(v.z) << 16;
      o.w = (u32)bf16rne(v.w) << 16;
      ((uint4*)hbuf)[gg] = o;
    } else {
      cvt4(x, xb, g - (3 * NWI + NH0));
    }
  }
}

// ---------------------------------------------------------------------------
// k_gemm: xp = x @ Wih^T + b_ih, written into d_out. (unchanged, verified)
// ---------------------------------------------------------------------------
template <bool XB>
__global__ __launch_bounds__(256) void k_gemm(const unsigned short* __restrict__ xbg,
                                              const float* __restrict__ xf,
                                              const unsigned short* __restrict__ Wb,
                                              const float* __restrict__ bias,
                                              float* __restrict__ C) {
  __shared__ __align__(16) unsigned short ldsA[128 * 64];
  __shared__ __align__(16) unsigned short ldsB[128 * 64];
  const int tid = threadIdx.x;
  const int w = tid >> 6, l = tid & 63;
  const int lr = l & 15, lk = l >> 4;
  const int n0 = (blockIdx.x & 7) * 128;
  const int m0 = (blockIdx.x >> 3) * 128;
  const int mbase = (w >> 1) * 64, nbase = (w & 1) * 64;

  f32x4 acc[4][4] = {};

  for (int kb = 0; kb < 16; ++kb) {
    const int k0 = kb * 64;
#pragma unroll
    for (int r = 0; r < 4; ++r) {
      int tb = r * 4096 + w * 1024 + l * 16;
      int row = tb >> 7;
      int p = (tb >> 4) & 7;
      int c = p ^ (row & 7);
      gll16(Wb + (u64)(n0 + row) * II_ + k0 + c * 8,
            (char*)ldsB + r * 4096 + w * 1024);
    }
    if constexpr (XB) {
#pragma unroll
      for (int r = 0; r < 4; ++r) {
        int tb = r * 4096 + w * 1024 + l * 16;
        int row = tb >> 7;
        int p = (tb >> 4) & 7;
        int c = p ^ (row & 7);
        gll16(xbg + (u64)(m0 + row) * II_ + k0 + c * 8,
              (char*)ldsA + r * 4096 + w * 1024);
      }
    } else {
      const int r = tid >> 1, ch = tid & 1;
      const float* gs = xf + (u64)(m0 + r) * II_ + k0 + ch * 32;
      float4 v[8];
#pragma unroll
      for (int q = 0; q < 8; ++q) v[q] = ((const float4*)gs)[q];
#pragma unroll
      for (int q = 0; q < 4; ++q) {
        int c = ch * 4 + q;
        int p = c ^ (r & 7);
        uint4 pk;
        pk.x = pk2(v[2 * q].x, v[2 * q].y);
        pk.y = pk2(v[2 * q].z, v[2 * q].w);
        pk.z = pk2(v[2 * q + 1].x, v[2 * q + 1].y);
        pk.w = pk2(v[2 * q + 1].z, v[2 * q + 1].w);
        *(uint4*)((char*)ldsA + r * 128 + p * 16) = pk;
      }
    }
    __syncthreads();

    bf16x8 a[4][2], b[4][2];
#pragma unroll
    for (int mt = 0; mt < 4; ++mt) {
      int row = mbase + mt * 16 + lr;
#pragma unroll
      for (int kk = 0; kk < 2; ++kk) {
        int c = kk * 4 + lk, p = c ^ (row & 7);
        a[mt][kk] = *(const bf16x8*)((const char*)ldsA + row * 128 + p * 16);
      }
    }
#pragma unroll
    for (int nt = 0; nt < 4; ++nt) {
      int row = nbase + nt * 16 + lr;
#pragma unroll
      for (int kk = 0; kk < 2; ++kk) {
        int c = kk * 4 + lk, p = c ^ (row & 7);
        b[nt][kk] = *(const bf16x8*)((const char*)ldsB + row * 128 + p * 16);
      }
    }
#pragma unroll
    for (int kk = 0; kk < 2; ++kk)
#pragma unroll
      for (int mt = 0; mt < 4; ++mt)
#pragma unroll
        for (int nt = 0; nt < 4; ++nt)
          acc[mt][nt] = __builtin_amdgcn_mfma_f32_16x16x32_bf16(a[mt][kk], b[nt][kk], acc[mt][nt], 0, 0, 0);
    __syncthreads();
  }

  float bn[4];
#pragma unroll
  for (int nt = 0; nt < 4; ++nt) bn[nt] = bias[n0 + nbase + nt * 16 + lr];
#pragma unroll
  for (int mt = 0; mt < 4; ++mt) {
#pragma unroll
    for (int i = 0; i < 4; ++i) {
      int m = m0 + mbase + mt * 16 + lk * 4 + i;
      float* cr = C + (u64)m * HH_ + n0 + nbase + lr;
#pragma unroll
      for (int nt = 0; nt < 4; ++nt) cr[nt * 16] = acc[mt][nt][i] + bn[nt];
    }
  }
}

// ---------------------------------------------------------------------------
// k_scan v4: tag-in-data protocol (r3) on r2 geometry (128 blocks = 32 j x 4
// batch domains), with weights PINNED IN AGPRs via inline-asm MFMA
// ("a"-constrained B operand -> allocator must use the accumulator file;
// VGPR pressure can no longer evict the 128-reg weight slice).
// Poll: initial 32-u64 load of the wave's own MFMA operands; group-masked
// exec-predicated retry reloads only stale 4-u64 groups (low LLC traffic).
// Skew safety: equality tags + double buffer; a block overwrites buffer
// words only after every domain block finished step t+1, i.e. after all
// readers of tag-(t+1) words are done. Cross-replay staleness is
// value-identical by determinism; first run sees 0xAA poison tags.
// ---------------------------------------------------------------------------
__global__ __launch_bounds__(256) void k_scan(float* __restrict__ out, const float* __restrict__ h0,
                                              const float* __restrict__ b1, const float* __restrict__ b2,
                                              const unsigned short* __restrict__ Wcat,
                                              u32* __restrict__ hbuf) {
  __shared__ float part[4 * 4 * 4 * 64];  // 16 KB [w][nt][i][lane]
  const int tid = threadIdx.x, w = tid >> 6, l = tid & 63;
  const int lr = l & 15, lk = l >> 4;
  const int og = blockIdx.x & 31, bg = blockIdx.x >> 5;
  const int jb = og * 32, bb = bg * 16;
  const int koff = w * 256;

  // --- weights: nt 0/1 -> W_hh1 cols jb..jb+31, nt 2/3 -> W_hh2 ---
  bf16x8 wt[4][8];
#pragma unroll
  for (int nt = 0; nt < 4; ++nt) {
    int nrow = (nt < 2) ? (jb + nt * 16 + lr) : (HH_ + jb + (nt - 2) * 16 + lr);
    const unsigned short* wr = Wcat + (u64)nrow * HH_ + koff + lk * 8;
#pragma unroll
    for (int kk = 0; kk < 8; ++kk) wt[nt][kk] = *(const bf16x8*)(wr + kk * 32);
  }

  // --- epilogue identity: this thread owns rows m0r,m0r+1 at col jcol ---
  const int jj = w & 1, i0 = (w >> 1) * 2;
  const int jloc = jj * 16 + lr;
  const int jcol = jb + jloc;
  const int m0r = lk * 4 + i0;
  const float bvA = b1[jcol], bvB = b2[jcol];
  float hold[2];
#pragma unroll
  for (int q = 0; q < 2; ++q) hold[q] = h0[(u64)(bb + m0r + q) * HH_ + jcol];

  const u64 myw = ((u64)(bb + lr) * HH_ + koff + lk * 8) >> 1;  // u64 index

  for (int t = 0; t < TT_; ++t) {
    // xp prefetch (latency hides under the poll)
    float xpv[2];
#pragma unroll
    for (int q = 0; q < 2; ++q)
      xpv[q] = out[((u64)(bb + m0r + q) * TT_ + t) * HH_ + jcol];

    // --- tagged poll: load own operand slice, retry only stale groups ---
    const u64* hB = (const u64*)hbuf + (u64)(t & 1) * (BB_ * HH_ / 2) + myw;
    const u32 expt = (u32)t;
    u64 qv[32];
#pragma unroll
    for (int kk = 0; kk < 8; ++kk)
#pragma unroll
      for (int q = 0; q < 4; ++q)
        qv[kk * 4 + q] = __hip_atomic_load(hB + kk * 16 + q, __ATOMIC_RELAXED, __HIP_MEMORY_SCOPE_AGENT);

    u32 gm = 0;
#pragma unroll
    for (int kk = 0; kk < 8; ++kk) {
      u32 bad = 0;
#pragma unroll
      for (int q = 0; q < 4; ++q) {
        u64 v = qv[kk * 4 + q];
        bad |= (((u32)v ^ expt) | ((u32)(v >> 32) ^ expt));
      }
      gm |= (u32)((bad & 0xFFFFu) != 0) << kk;
    }
    while (__any((int)gm)) {
#pragma unroll
      for (int kk = 0; kk < 8; ++kk) {
        if (gm & (1u << kk)) {  // exec-masked: only stale lanes re-fetch
          u32 bad = 0;
#pragma unroll
          for (int q = 0; q < 4; ++q) {
            u64 v = __hip_atomic_load(hB + kk * 16 + q, __ATOMIC_RELAXED, __HIP_MEMORY_SCOPE_AGENT);
            qv[kk * 4 + q] = v;
            bad |= (((u32)v ^ expt) | ((u32)(v >> 32) ^ expt));
          }
          if (!(bad & 0xFFFFu)) gm &= ~(1u << kk);
        }
      }
    }

    // --- unpack payload high-halves -> bf16 A-fragments (r3-verified perm) ---
    bf16x8 av[8];
#pragma unroll
    for (int kk = 0; kk < 8; ++kk) {
      union { u32 u[4]; bf16x8 v; } au;
#pragma unroll
      for (int q = 0; q < 4; ++q) {
        u64 d = qv[kk * 4 + q];
        au.u[q] = __builtin_amdgcn_perm((u32)(d >> 32), (u32)d, 0x07060302);
      }
      av[kk] = au.v;
    }

    // --- MFMA with AGPR-pinned weights ---
    f32x4 acc[4] = {};
#pragma unroll
    for (int kk = 0; kk < 8; ++kk)
#pragma unroll
      for (int nt = 0; nt < 4; ++nt)
        asm("v_mfma_f32_16x16x32_bf16 %0, %1, %2, %0"
            : "+v"(acc[nt]) : "v"(av[kk]), "a"(wt[nt][kk]));
    asm volatile("s_nop 7\ns_nop 7"
                 :: "v"(acc[0][0]), "v"(acc[1][0]), "v"(acc[2][0]), "v"(acc[3][0]));

    // --- cross-wave K-reduction via LDS (conflict-free stride-1) ---
#pragma unroll
    for (int nt = 0; nt < 4; ++nt)
#pragma unroll
      for (int i = 0; i < 4; ++i)
        part[((w * 4 + nt) * 4 + i) * 64 + l] = acc[nt][i];
    __syncthreads();

    float s1[2], s2[2];
#pragma unroll
    for (int q = 0; q < 2; ++q) {
      float a1 = 0.f, a2 = 0.f;
#pragma unroll
      for (int ww = 0; ww < 4; ++ww) {
        a1 += part[((ww * 4 + jj) * 4 + i0 + q) * 64 + l];
        a2 += part[((ww * 4 + jj + 2) * 4 + i0 + q) * 64 + l];
      }
      s1[q] = a1; s2[q] = a2;
    }
    __syncthreads();  // part[] WAR for next step

    // --- gates + stores (tagged h broadcast, fire-and-forget) ---
#pragma unroll
    for (int q = 0; q < 2; ++q) {
      float t1 = tanhfast(s1[q] + xpv[q] + bvA);
      float t2 = tanhfast(s2[q] + xpv[q] + bvB);
      float hn = t1 + hold[q] * (t2 - t1);  // (1-h)*v1 + h*v2
      hold[q] = hn;
      out[((u64)(bb + m0r + q) * TT_ + t) * HH_ + jcol] = hn;
      if (t < TT_ - 1) {
        u32 tg = ((u32)bf16rne(hn) << 16) | (u32)(t + 1);
        __hip_atomic_store(hbuf + (u64)((t + 1) & 1) * (BB_ * HH_) + (u64)(bb + m0r + q) * HH_ + jcol,
                           tg, __ATOMIC_RELAXED, __HIP_MEMORY_SCOPE_AGENT);
      } else {
        out[(u64)BB_ * TT_ * HH_ + (u64)(bb + m0r + q) * HH_ + jcol] = hn;
      }
    }
  }
}

// ---------------------------------------------------------------------------
extern "C" void kernel_launch(void* const* d_in, const int* in_sizes, int n_in,
                              void* d_out, int out_size, void* d_ws, size_t ws_size,
                              hipStream_t stream) {
  const float* x    = (const float*)d_in[0];
  const float* h0   = (const float*)d_in[1];
  const float* Wih  = (const float*)d_in[2];
  const float* bih  = (const float*)d_in[3];
  const float* Whh1 = (const float*)d_in[4];
  const float* bhh1 = (const float*)d_in[5];
  const float* Whh2 = (const float*)d_in[6];
  const float* bhh2 = (const float*)d_in[7];
  float* out = (float*)d_out;

  char* ws = (char*)d_ws;
  unsigned short* Wihb  = (unsigned short*)(ws + 0);          //  2 MiB
  unsigned short* Wcatb = (unsigned short*)(ws + 2097152);    //  4 MiB
  u32*            hbuf  = (u32*)(ws + 6291456);               //  512 KiB (2 tagged buffers)
  unsigned short* xb    = (unsigned short*)(ws + 6815744);    //  64 MiB
  const bool fastx = ws_size >= 73924608ULL;

  hipLaunchKernelGGL(k_convert, dim3(2048), dim3(256), 0, stream,
                     x, h0, Wih, Whh1, Whh2, xb, Wihb, Wcatb, hbuf, (int)fastx);
  if (fastx)
    hipLaunchKernelGGL((k_gemm<true>), dim3(2048), dim3(256), 0, stream,
                       xb, (const float*)nullptr, Wihb, bih, out);
  else
    hipLaunchKernelGGL((k_gemm<false>), dim3(2048), dim3(256), 0, stream,
                       (const unsigned short*)nullptr, x, Wihb, bih, out);
  hipLaunchKernelGGL(k_scan, dim3(NSCAN_BLOCKS), dim3(256), 0, stream,
                     out, h0, bhh1, bhh2, Wcatb, hbuf);
}